// Round 11
// baseline (1251.795 us; speedup 1.0000x reference)
//
#include <hip/hip_runtime.h>
#include <math.h>

typedef unsigned short u16;
typedef unsigned int u32;
typedef unsigned long long u64;

// dims
#define NB 4
#define NT 256
#define NN 48
#define NF 4
#define NH 64
#define NK 4
#define NE 192
#define NLH 512
#define NC 8
#define NG 1024          // B*T
#define KH 256           // K*H
#define SEQD 3072        // N*H
#define G4 2048          // 4*LH
#define LSTM_NBLK 64
#define XS 520           // padded xlds row stride (bf16): 1040B = 260 words = 4 mod 32 banks

typedef __attribute__((ext_vector_type(8))) short bf16x8;
typedef __attribute__((ext_vector_type(4))) float f32x4;

__device__ __forceinline__ float bf2f(u16 v) {
  union { u32 u; float f; } c; c.u = ((u32)v) << 16; return c.f;
}
__device__ __forceinline__ u16 f2bf(float f) {
  union { float f; u32 u; } c; c.f = f;
  u32 r = c.u + 0x7FFFu + ((c.u >> 16) & 1u);
  return (u16)(r >> 16);
}
__device__ __forceinline__ u32 fbits(float f) { union { float f; u32 u; } c; c.f = f; return c.u; }
__device__ __forceinline__ float bitsf(u32 u) { union { u32 u; float f; } c; c.u = u; return c.f; }

// fast transcendentals (validated rounds 2/3/5/6/7/10: absmax unchanged)
__device__ __forceinline__ float sigm_fast(float x) {
  return 1.f / (1.f + __expf(-x));
}
__device__ __forceinline__ float tanh_fast(float x) {
  float ax = fabsf(x);
  float t = __expf(-2.f * ax);          // in (0,1], never inf
  float r = (1.f - t) / (1.f + t);
  return x < 0.f ? -r : r;
}

// ---------------- kernel 0: merged prep (wihb | wtc | setup) ----------------
// Blocks 0..3071: Wih f32->bf16. Blocks 3072..3199: WTc build.
// Block 3200: parallel CSR build. One launch instead of three serialized ones.
__global__ __launch_bounds__(256) void prep_kernel(
    const float* __restrict__ Wih, u16* __restrict__ WihB,
    const float* __restrict__ Wl2, const float* __restrict__ Wr2,
    u16* __restrict__ WTc,
    const int* __restrict__ ei, int* __restrict__ coff, int* __restrict__ ceid)
{
  const int blk = blockIdx.x;
  const int tid = threadIdx.x;
  if (blk < 3072) {
    int id = (blk * 256 + tid) * 8;
    float4 a = *(const float4*)(Wih + id);
    float4 b = *(const float4*)(Wih + id + 4);
    u16* dst = WihB + id;
    dst[0] = f2bf(a.x); dst[1] = f2bf(a.y); dst[2] = f2bf(a.z); dst[3] = f2bf(a.w);
    dst[4] = f2bf(b.x); dst[5] = f2bf(b.y); dst[6] = f2bf(b.z); dst[7] = f2bf(b.w);
  } else if (blk < 3200) {
    int id0 = (blk - 3072) * 256 + tid;
#pragma unroll
    for (int rep = 0; rep < 4; ++rep) {
      int id = id0 + rep * 32768;             // id = n*256 + k
      int n = id >> 8, k = id & 255;
      float v = (n < 256) ? Wl2[k * 256 + n] : Wr2[k * 256 + (n - 256)];
      WTc[id] = f2bf(v);
    }
  } else {
    // CSR build (by dst); barriers are inside a block-uniform branch => legal
    __shared__ int sdst[NE];
    __shared__ int scnt[NN + 1];
    if (tid < NE) sdst[tid] = ei[NE + tid];
    if (tid < NN + 1) scnt[tid] = 0;
    __syncthreads();
    if (tid < NN) {
      int c = 0;
      for (int e = 0; e < NE; ++e) c += (sdst[e] == tid) ? 1 : 0;
      scnt[tid + 1] = c;
    }
    __syncthreads();
    if (tid == 0) {
      int acc = 0;
      coff[0] = 0;
#pragma unroll
      for (int n = 0; n < NN; ++n) {
        acc += scnt[n + 1];
        scnt[n + 1] = acc;
        coff[n + 1] = acc;
      }
    }
    __syncthreads();
    if (tid < NN) {
      int p = scnt[tid];                // start offset for node tid
      for (int e = 0; e < NE; ++e)
        if (sdst[e] == tid) ceid[p++] = e;
    }
  }
}

// ---------------- kernel 1: fused GATv2 L1+L2 (MFMA mid-section) ------------
// LDS tile xlds[48][XS=520] (bf16), padded row stride; edge scores
// vectorized bf16x8 (identical FP summation order). (round-7 proven version)
__global__ __launch_bounds__(256) void gat_fused_kernel(
    const float* __restrict__ x, const int* __restrict__ ei,
    const int* __restrict__ coff, const int* __restrict__ ceid,
    const float* __restrict__ Wl1, const float* __restrict__ Wr1,
    const float* __restrict__ att1, const float* __restrict__ b1,
    const u16* __restrict__ WTc,
    const float* __restrict__ att2, const float* __restrict__ b2,
    u16* __restrict__ h2b)
{
  __shared__ __attribute__((aligned(16))) u16 xlds[NN * XS];   // 48.75KB
  __shared__ float sWl1[NF * KH], sWr1[NF * KH];   // 8KB
  __shared__ float satt[KH];            // att1 then att2
  __shared__ float sbias[KH];           // b1 then b2
  __shared__ float sx[NN * NF];
  __shared__ float esc[NE * NK];
  __shared__ int soff[NN + 1];
  __shared__ u16 seid[NE], ssrc[NE], sdst[NE];

  const int tid = threadIdx.x;
  const int g = blockIdx.x;
  const int lane = tid & 63, wv = tid >> 6;
  const int l15 = lane & 15, q = lane >> 4;

#pragma unroll
  for (int rep = 0; rep < 4; ++rep) {
    int idx = rep * 256 + tid;
    sWl1[idx] = Wl1[idx];
    sWr1[idx] = Wr1[idx];
  }
  satt[tid] = att1[tid];
  sbias[tid] = b1[tid];
  if (tid < NN * NF) sx[tid] = x[(size_t)g * (NN * NF) + tid];
  if (tid < NE) {
    ssrc[tid] = (u16)ei[tid];
    sdst[tid] = (u16)ei[NE + tid];
    seid[tid] = (u16)ceid[tid];
  }
  if (tid < NN + 1) soff[tid] = coff[tid];
  __syncthreads();

  // ---- L1 transforms once: thread owns column o=tid ----
  {
    float w0 = sWl1[tid], w1 = sWl1[256 + tid], w2 = sWl1[512 + tid], w3 = sWl1[768 + tid];
    float v0 = sWr1[tid], v1 = sWr1[256 + tid], v2 = sWr1[512 + tid], v3 = sWr1[768 + tid];
#pragma unroll 4
    for (int n = 0; n < NN; ++n) {
      float x0 = sx[n * 4 + 0], x1 = sx[n * 4 + 1], x2 = sx[n * 4 + 2], x3 = sx[n * 4 + 3];
      float xl = fmaf(x3, w3, fmaf(x2, w2, fmaf(x1, w1, x0 * w0)));
      float xr = fmaf(x3, v3, fmaf(x2, v2, fmaf(x1, v1, x0 * v0)));
      xlds[n * XS + tid] = f2bf(xl);
      xlds[n * XS + 256 + tid] = f2bf(xr);
    }
  }
  __syncthreads();

  // ---- L1 edge scores (vectorized bf16x8) ----
  for (int e = tid; e < NE; e += 256) {
    int s = ssrc[e], d = sdst[e];
    const u16* xls = xlds + s * XS;
    const u16* xrd = xlds + d * XS + 256;
#pragma unroll
    for (int k = 0; k < 4; ++k) {
      float acc = 0.f;
#pragma unroll
      for (int c = 0; c < 8; ++c) {
        bf16x8 av = *(const bf16x8*)(xls + k * 64 + c * 8);
        bf16x8 bv = *(const bf16x8*)(xrd + k * 64 + c * 8);
        const float* ap = satt + k * 64 + c * 8;
#pragma unroll
        for (int j = 0; j < 8; ++j) {
          float tv = bf2f((u16)av[j]) + bf2f((u16)bv[j]);
          tv = tv > 0.f ? tv : 0.2f * tv;
          acc = fmaf(tv, ap[j], acc);
        }
      }
      esc[e * 4 + k] = acc;
    }
  }
  __syncthreads();

  // ---- L1 softmax per (n,k) ----
  if (tid < NN * NK) {
    int n = tid >> 2, k = tid & 3;
    int e0 = soff[n], e1 = soff[n + 1];
    if (e1 > e0) {
      float m = -1e30f;
      for (int j = e0; j < e1; ++j) m = fmaxf(m, esc[seid[j] * 4 + k]);
      float den = 0.f;
      for (int j = e0; j < e1; ++j) {
        float pv = expf(esc[seid[j] * 4 + k] - m);
        esc[seid[j] * 4 + k] = pv;
        den += pv;
      }
      float inv = 1.f / (den + 1e-16f);
      for (int j = e0; j < e1; ++j) esc[seid[j] * 4 + k] *= inv;
    }
  }
  __syncthreads();

  // ---- L1 aggregate -> h1 bf16 into cols 256-511 (xr dead); att2 reload ----
  satt[tid] = att2[tid];
  {
    int o = tid, k = o >> 6;
    for (int n = 0; n < NN; ++n) {
      int e0 = soff[n], e1 = soff[n + 1];
      float acc = 0.f;
      for (int j = e0; j < e1; ++j) {
        int e = seid[j];
        int s = ssrc[e];
        acc = fmaf(esc[e * 4 + k], bf2f(xlds[s * XS + o]), acc);
      }
      float ov = acc + sbias[o];
      xlds[n * XS + 256 + o] = f2bf(fmaxf(ov, 0.f));
    }
  }
  __syncthreads();
  if (tid < NH) sbias[tid] = b2[tid];

  // ---- MFMA: A-frags (h1) from LDS into VGPRs ----
  bf16x8 afr[3][8];
#pragma unroll
  for (int mt = 0; mt < 3; ++mt)
#pragma unroll
    for (int kt = 0; kt < 8; ++kt)
      afr[mt][kt] = *(const bf16x8*)(xlds + (mt * 16 + l15) * XS + 256 + kt * 32 + q * 8);
  __syncthreads();   // all A-frags in regs before outputs overwrite the tile

  // wave wv owns n-tiles [wv*8, wv*8+8)
#pragma unroll
  for (int t = 0; t < 8; ++t) {
    int n0 = (wv * 8 + t) * 16;
    const u16* bcol = WTc + (size_t)(n0 + l15) * KH + q * 8;
    f32x4 acc0 = {0.f, 0.f, 0.f, 0.f}, acc1 = acc0, acc2 = acc0;
#pragma unroll
    for (int kt = 0; kt < 8; ++kt) {
      bf16x8 bfr = *(const bf16x8*)(bcol + kt * 32);
      acc0 = __builtin_amdgcn_mfma_f32_16x16x32_bf16(afr[0][kt], bfr, acc0, 0, 0, 0);
      acc1 = __builtin_amdgcn_mfma_f32_16x16x32_bf16(afr[1][kt], bfr, acc1, 0, 0, 0);
      acc2 = __builtin_amdgcn_mfma_f32_16x16x32_bf16(afr[2][kt], bfr, acc2, 0, 0, 0);
    }
#pragma unroll
    for (int r = 0; r < 4; ++r) {
      int rw = q * 4 + r;
      xlds[(0 * 16 + rw) * XS + n0 + l15] = f2bf(acc0[r]);
      xlds[(1 * 16 + rw) * XS + n0 + l15] = f2bf(acc1[r]);
      xlds[(2 * 16 + rw) * XS + n0 + l15] = f2bf(acc2[r]);
    }
  }
  __syncthreads();

  // ---- L2 edge scores (vectorized bf16x8) ----
  for (int e = tid; e < NE; e += 256) {
    int s = ssrc[e], d = sdst[e];
    const u16* xls = xlds + s * XS;
    const u16* xrd = xlds + d * XS + 256;
#pragma unroll
    for (int k = 0; k < 4; ++k) {
      float acc = 0.f;
#pragma unroll
      for (int c = 0; c < 8; ++c) {
        bf16x8 av = *(const bf16x8*)(xls + k * 64 + c * 8);
        bf16x8 bv = *(const bf16x8*)(xrd + k * 64 + c * 8);
        const float* ap = satt + k * 64 + c * 8;
#pragma unroll
        for (int j = 0; j < 8; ++j) {
          float tv = bf2f((u16)av[j]) + bf2f((u16)bv[j]);
          tv = tv > 0.f ? tv : 0.2f * tv;
          acc = fmaf(tv, ap[j], acc);
        }
      }
      esc[e * 4 + k] = acc;
    }
  }
  __syncthreads();

  // ---- L2 softmax ----
  if (tid < NN * NK) {
    int n = tid >> 2, k = tid & 3;
    int e0 = soff[n], e1 = soff[n + 1];
    if (e1 > e0) {
      float m = -1e30f;
      for (int j = e0; j < e1; ++j) m = fmaxf(m, esc[seid[j] * 4 + k]);
      float den = 0.f;
      for (int j = e0; j < e1; ++j) {
        float pv = expf(esc[seid[j] * 4 + k] - m);
        esc[seid[j] * 4 + k] = pv;
        den += pv;
      }
      float inv = 1.f / (den + 1e-16f);
      for (int j = e0; j < e1; ++j) esc[seid[j] * 4 + k] *= inv;
    }
  }
  __syncthreads();

  // ---- L2 aggregate, mean over k, +bias, relu -> h2 bf16 global ----
  for (int task = tid; task < NN * NH; task += 256) {
    int n = task >> 6, h = task & 63;
    int e0 = soff[n], e1 = soff[n + 1];
    float acc = 0.f;
    for (int j = e0; j < e1; ++j) {
      int e = seid[j];
      int s = ssrc[e];
      const u16* xls = xlds + s * XS + h;
#pragma unroll
      for (int k = 0; k < 4; ++k)
        acc = fmaf(esc[e * 4 + k], bf2f(xls[k * 64]), acc);
    }
    float ov = fmaf(acc, 0.25f, sbias[h]);
    h2b[(size_t)g * SEQD + task] = f2bf(fmaxf(ov, 0.f));
  }
}

// ---------------- kernel 3: xw = seq @ W_ih^T + bias, bf16 MFMA -------------
// Grid 256 blocks (16 gt x 16 rt), tile M=64 x N=128, 256 threads (4 waves).
__global__ __launch_bounds__(256) void xw_mfma_kernel(const u16* __restrict__ h2b,
                                                      const u16* __restrict__ WihB,
                                                      const float* __restrict__ bih,
                                                      const float* __restrict__ bhh,
                                                      float* __restrict__ xw)
{
  const int tid = threadIdx.x, lane = tid & 63, wv = tid >> 6;
  const int l15 = lane & 15, q = lane >> 4;
  const int gt = blockIdx.x & 15, rt = blockIdx.x >> 4;
  const int g0 = gt * 64, r0 = rt * 128;

  const u16* arow[4];
#pragma unroll
  for (int mt = 0; mt < 4; ++mt)
    arow[mt] = h2b + (size_t)(g0 + mt * 16 + l15) * SEQD + q * 8;
  const u16* brow[2];
  int ncol[2];
#pragma unroll
  for (int tn = 0; tn < 2; ++tn) {
    ncol[tn] = r0 + (wv * 2 + tn) * 16 + l15;
    brow[tn] = WihB + (size_t)ncol[tn] * SEQD + q * 8;
  }

  f32x4 acc[4][2];
#pragma unroll
  for (int mt = 0; mt < 4; ++mt)
#pragma unroll
    for (int tn = 0; tn < 2; ++tn) acc[mt][tn] = (f32x4){0.f, 0.f, 0.f, 0.f};

  for (int kt = 0; kt < SEQD / 32; ++kt) {
    bf16x8 af[4], bfv[2];
#pragma unroll
    for (int mt = 0; mt < 4; ++mt) af[mt] = *(const bf16x8*)(arow[mt] + kt * 32);
#pragma unroll
    for (int tn = 0; tn < 2; ++tn) bfv[tn] = *(const bf16x8*)(brow[tn] + kt * 32);
#pragma unroll
    for (int mt = 0; mt < 4; ++mt)
#pragma unroll
      for (int tn = 0; tn < 2; ++tn)
        acc[mt][tn] = __builtin_amdgcn_mfma_f32_16x16x32_bf16(af[mt], bfv[tn], acc[mt][tn], 0, 0, 0);
  }

#pragma unroll
  for (int tn = 0; tn < 2; ++tn) {
    float bias = bih[ncol[tn]] + bhh[ncol[tn]];
#pragma unroll
    for (int mt = 0; mt < 4; ++mt)
#pragma unroll
      for (int r = 0; r < 4; ++r) {
        int gg = g0 + mt * 16 + q * 4 + r;
        xw[(size_t)gg * G4 + ncol[tn]] = acc[mt][tn][r] + bias;
      }
  }
}

// ---------------- kernel 4: persistent LSTM + FC, self-validating pairs -----
// Single barrier per step; pair-split finish (round-10 proven). NEW: poll is
// double-buffered (two 8-load batches in flight, phase-shifted) => effective
// stamp-sampling interval ~RTT/2, halving max-over-blocks detection
// overshoot. Protocol (stamped u64 pairs, 2-deep parity) unchanged.
__global__ __launch_bounds__(256) void lstm_kernel(const float* __restrict__ xw,
                                                   const float* __restrict__ Whh,
                                                   const float* __restrict__ fcw,
                                                   const float* __restrict__ fcb,
                                                   u64* pairs,
                                                   float* __restrict__ out)
{
  __shared__ float hlds[NB * NLH];     // 8KB
  __shared__ float part[2][8][32][4];  // 8KB, parity-buffered
  __shared__ float clds[8][4];
  __shared__ float fcpart[32][8];

  const int tid = threadIdx.x;
  const int blk = blockIdx.x;
  const int r32 = tid & 31, p = tid >> 5;
  const int lane = tid & 63, w = tid >> 6;
  const int R = (r32 >> 3) * NLH + blk * 8 + (r32 & 7);

  // finish mapping (wave 0, lane pairs): lane = fb*16 + fu*2 + fh
  const int fb = lane >> 4;            // batch 0..3
  const int fu = (lane >> 1) & 7;      // unit_local 0..7
  const int fh = lane & 1;             // half: gates {2fh, 2fh+1}

  float wreg[64];
  {
    const float4* wsrc = (const float4*)(Whh + (size_t)R * NLH + p * 64);
#pragma unroll
    for (int q = 0; q < 16; ++q) {
      float4 v = wsrc[q];
      wreg[4 * q + 0] = v.x; wreg[4 * q + 1] = v.y;
      wreg[4 * q + 2] = v.z; wreg[4 * q + 3] = v.w;
    }
  }
  if (tid < 32) {
    int u = tid & 7, b = tid >> 3;
    clds[u][b] = 0.f;
    __hip_atomic_store(&pairs[0 * (NB * NLH) + b * NLH + blk * 8 + u], 0ULL,
                       __ATOMIC_RELAXED, __HIP_MEMORY_SCOPE_AGENT);
  }

#define POLL_LOADS(dst)                                                        \
  _Pragma("unroll")                                                            \
  for (int b = 0; b < NB; ++b) {                                               \
    dst[2 * b]     = __hip_atomic_load(&pb[b * NLH + u0],                      \
                                       __ATOMIC_RELAXED, __HIP_MEMORY_SCOPE_AGENT); \
    dst[2 * b + 1] = __hip_atomic_load(&pb[b * NLH + u1],                      \
                                       __ATOMIC_RELAXED, __HIP_MEMORY_SCOPE_AGENT); \
  }
#define POLL_OK(src, need, okv)                                                \
  {                                                                            \
    int mn = 0x7fffffff;                                                       \
    _Pragma("unroll")                                                          \
    for (int q2 = 0; q2 < 8; ++q2) mn = min(mn, (int)(u32)(src[q2] >> 32));    \
    okv = __all(mn >= (need));                                                 \
  }
#define STORE_H(src)                                                           \
  _Pragma("unroll")                                                            \
  for (int b = 0; b < NB; ++b) {                                               \
    hlds[b * NLH + u0] = bitsf((u32)src[2 * b]);                               \
    hlds[b * NLH + u1] = bitsf((u32)src[2 * b + 1]);                           \
  }

  for (int s = 0; s < NT; ++s) {
    // xw preload: each finish lane loads its 2 gate values (overlaps the poll)
    float myxw0, myxw1;
    if (tid < 64) {
      int un = blk * 8 + fu;
      const float* xr = xw + (size_t)(fb * NT + s) * G4 + un;
      myxw0 = xr[(2 * fh) * NLH];
      myxw1 = xr[(2 * fh + 1) * NLH];
    }
    // double-buffered poll: wave w fetches its 128 units x 4 batches
    {
      u64* pb = pairs + (size_t)(s & 1) * (NB * NLH);
      const int u0 = w * 128 + lane, u1 = u0 + 64;
      u64 va[8], vb[8];
      int ok;
      POLL_LOADS(va);
      for (;;) {
        POLL_LOADS(vb);               // in flight while we check va
        POLL_OK(va, s, ok);
        if (ok) { STORE_H(va); break; }
        POLL_LOADS(va);               // in flight while we check vb
        POLL_OK(vb, s, ok);
        if (ok) { STORE_H(vb); break; }
      }
    }
    // wave-local: hlds segment written and read only by wave w

    float a0 = 0.f, a1 = 0.f, a2 = 0.f, a3 = 0.f;
    const float* h0 = &hlds[0 * NLH + p * 64];
    const float* h1p = &hlds[1 * NLH + p * 64];
    const float* h2p = &hlds[2 * NLH + p * 64];
    const float* h3p = &hlds[3 * NLH + p * 64];
#pragma unroll
    for (int j = 0; j < 16; ++j) {
      float w0 = wreg[4 * j], w1 = wreg[4 * j + 1], w2 = wreg[4 * j + 2], w3 = wreg[4 * j + 3];
      float4 v0 = *(const float4*)(h0 + 4 * j);
      float4 v1 = *(const float4*)(h1p + 4 * j);
      float4 v2 = *(const float4*)(h2p + 4 * j);
      float4 v3 = *(const float4*)(h3p + 4 * j);
      a0 = fmaf(v0.w, w3, fmaf(v0.z, w2, fmaf(v0.y, w1, fmaf(v0.x, w0, a0))));
      a1 = fmaf(v1.w, w3, fmaf(v1.z, w2, fmaf(v1.y, w1, fmaf(v1.x, w0, a1))));
      a2 = fmaf(v2.w, w3, fmaf(v2.z, w2, fmaf(v2.y, w1, fmaf(v2.x, w0, a2))));
      a3 = fmaf(v3.w, w3, fmaf(v3.z, w2, fmaf(v3.y, w1, fmaf(v3.x, w0, a3))));
    }
    float (*pt)[32][4] = part[s & 1];
    pt[p][r32][0] = a0; pt[p][r32][1] = a1;
    pt[p][r32][2] = a2; pt[p][r32][3] = a3;
    __syncthreads();                                  // single barrier
    if (tid < 64) {
      // each lane sums its 2 gate rows (same pp order as before)
      float t0 = myxw0, t1 = myxw1;
      const int row0 = (2 * fh) * 8 + fu, row1 = (2 * fh + 1) * 8 + fu;
#pragma unroll
      for (int pp = 0; pp < 8; ++pp) t0 += pt[pp][row0][fb];
#pragma unroll
      for (int pp = 0; pp < 8; ++pp) t1 += pt[pp][row1][fb];
      // even lane: t0=i, t1=f; odd lane: t0=g, t1=o
      float e0 = fh ? tanh_fast(t0) : sigm_fast(t0);   // si | tanh(g)
      float e1 = sigm_fast(t1);                        // sf | so
      float tg = __shfl_xor(e0, 1);   // even lane receives tanh(g)
      float so = __shfl_xor(e1, 1);   // even lane receives sigm(o)
      if (fh == 0) {
        float cn = fmaf(e1, clds[fu][fb], e0 * tg);
        float hn = so * tanh_fast(cn);
        clds[fu][fb] = cn;
        u64 pk = ((u64)(u32)(s + 1) << 32) | (u64)fbits(hn);
        __hip_atomic_store(&pairs[(size_t)((s + 1) & 1) * (NB * NLH) + fb * NLH + blk * 8 + fu],
                           pk, __ATOMIC_RELAXED, __HIP_MEMORY_SCOPE_AGENT);
      }
    }
  }

  // FC on block 0
  if (blk == 0) {
    {
      u64* pb = pairs + (size_t)(NT & 1) * (NB * NLH);
      const int u0 = w * 128 + lane, u1 = u0 + 64;
      u64 va[8];
      int ok;
      for (;;) {
        POLL_LOADS(va);
        POLL_OK(va, NT, ok);
        if (ok) { STORE_H(va); break; }
      }
    }
    __syncthreads();
    int pr = tid >> 3, l = tid & 7;
    int b = pr >> 3, cc = pr & 7;
    const float* hf = hlds + b * NLH;
    float a = 0.f;
    int base = cc * NLH + l * 64;
    for (int j = 0; j < 64; ++j) a = fmaf(hf[l * 64 + j], fcw[base + j], a);
    fcpart[pr][l] = a;
    __syncthreads();
    if (tid < 32) {
      float s = fcb[tid & 7];
#pragma unroll
      for (int l2 = 0; l2 < 8; ++l2) s += fcpart[tid][l2];
      out[tid] = s;
    }
  }
#undef POLL_LOADS
#undef POLL_OK
#undef STORE_H
}

// ---------------- host ----------------
extern "C" void kernel_launch(void* const* d_in, const int* in_sizes, int n_in,
                              void* d_out, int out_size, void* d_ws, size_t ws_size,
                              hipStream_t stream)
{
  (void)in_sizes; (void)n_in; (void)out_size; (void)ws_size;
  const float* x    = (const float*)d_in[0];
  const int*   ei   = (const int*)d_in[1];
  const float* Wl1  = (const float*)d_in[2];
  const float* Wr1  = (const float*)d_in[3];
  const float* att1 = (const float*)d_in[4];
  const float* b1   = (const float*)d_in[5];
  const float* Wl2  = (const float*)d_in[6];
  const float* Wr2  = (const float*)d_in[7];
  const float* att2 = (const float*)d_in[8];
  const float* b2   = (const float*)d_in[9];
  const float* Wih  = (const float*)d_in[10];
  const float* Whh  = (const float*)d_in[11];
  const float* bih  = (const float*)d_in[12];
  const float* bhh  = (const float*)d_in[13];
  const float* fcw  = (const float*)d_in[14];
  const float* fcb  = (const float*)d_in[15];

  // workspace layout (~27.6 MB)
  char* ws = (char*)d_ws;
  int* csr_off = (int*)(ws + 0);                    // 49 ints
  int* csr_eid = (int*)(ws + 256);                  // 192 ints -> ends 1024
  u64* pairs   = (u64*)(ws + 1024);                 // 32KB -> 33792
  u16* WTc     = (u16*)(ws + 40960);                // 256KB -> 303104
  u16* WihB    = (u16*)(ws + 303104);               // 12.6MB -> 12886016
  u16* h2b     = (u16*)(ws + 12886016);             // 6MB -> 19177472
  float* xwb   = (float*)(ws + 19177472);           // 8MB -> 27566080
  float* outp  = (float*)d_out;

  prep_kernel<<<3201, 256, 0, stream>>>(Wih, WihB, Wl2, Wr2, WTc,
                                        ei, csr_off, csr_eid);
  gat_fused_kernel<<<NG, 256, 0, stream>>>(x, ei, csr_off, csr_eid,
                                           Wl1, Wr1, att1, b1,
                                           WTc, att2, b2, h2b);
  xw_mfma_kernel<<<256, 256, 0, stream>>>(h2b, WihB, bih, bhh, xwb);
  lstm_kernel<<<LSTM_NBLK, 256, 0, stream>>>(xwb, Whh, fcw, fcb, pairs, outp);
}

// Round 12
// 1137.445 us; speedup vs baseline: 1.1005x; 1.1005x over previous
//
#include <hip/hip_runtime.h>
#include <math.h>

typedef unsigned short u16;
typedef unsigned int u32;
typedef unsigned long long u64;

// dims
#define NB 4
#define NT 256
#define NN 48
#define NF 4
#define NH 64
#define NK 4
#define NE 192
#define NLH 512
#define NC 8
#define NG 1024          // B*T
#define KH 256           // K*H
#define SEQD 3072        // N*H
#define G4 2048          // 4*LH
#define LSTM_NBLK 64
#define XS 520           // padded xlds row stride (bf16): 1040B = 260 words = 4 mod 32 banks

typedef __attribute__((ext_vector_type(8))) short bf16x8;
typedef __attribute__((ext_vector_type(4))) float f32x4;

__device__ __forceinline__ float bf2f(u16 v) {
  union { u32 u; float f; } c; c.u = ((u32)v) << 16; return c.f;
}
__device__ __forceinline__ u16 f2bf(float f) {
  union { float f; u32 u; } c; c.f = f;
  u32 r = c.u + 0x7FFFu + ((c.u >> 16) & 1u);
  return (u16)(r >> 16);
}
__device__ __forceinline__ u32 fbits(float f) { union { float f; u32 u; } c; c.f = f; return c.u; }
__device__ __forceinline__ float bitsf(u32 u) { union { u32 u; float f; } c; c.u = u; return c.f; }

// fast transcendentals (validated rounds 2/3/5/6/7/10: absmax unchanged)
__device__ __forceinline__ float sigm_fast(float x) {
  return 1.f / (1.f + __expf(-x));
}
__device__ __forceinline__ float tanh_fast(float x) {
  float ax = fabsf(x);
  float t = __expf(-2.f * ax);          // in (0,1], never inf
  float r = (1.f - t) / (1.f + t);
  return x < 0.f ? -r : r;
}

// ---------------- kernel 0: merged prep (wihb | wtc | setup) ----------------
// Blocks 0..3071: Wih f32->bf16. Blocks 3072..3199: WTc build.
// Block 3200: parallel CSR build. One launch instead of three serialized ones.
// (validated round 11)
__global__ __launch_bounds__(256) void prep_kernel(
    const float* __restrict__ Wih, u16* __restrict__ WihB,
    const float* __restrict__ Wl2, const float* __restrict__ Wr2,
    u16* __restrict__ WTc,
    const int* __restrict__ ei, int* __restrict__ coff, int* __restrict__ ceid)
{
  const int blk = blockIdx.x;
  const int tid = threadIdx.x;
  if (blk < 3072) {
    int id = (blk * 256 + tid) * 8;
    float4 a = *(const float4*)(Wih + id);
    float4 b = *(const float4*)(Wih + id + 4);
    u16* dst = WihB + id;
    dst[0] = f2bf(a.x); dst[1] = f2bf(a.y); dst[2] = f2bf(a.z); dst[3] = f2bf(a.w);
    dst[4] = f2bf(b.x); dst[5] = f2bf(b.y); dst[6] = f2bf(b.z); dst[7] = f2bf(b.w);
  } else if (blk < 3200) {
    int id0 = (blk - 3072) * 256 + tid;
#pragma unroll
    for (int rep = 0; rep < 4; ++rep) {
      int id = id0 + rep * 32768;             // id = n*256 + k
      int n = id >> 8, k = id & 255;
      float v = (n < 256) ? Wl2[k * 256 + n] : Wr2[k * 256 + (n - 256)];
      WTc[id] = f2bf(v);
    }
  } else {
    // CSR build (by dst); barriers are inside a block-uniform branch => legal
    __shared__ int sdst[NE];
    __shared__ int scnt[NN + 1];
    if (tid < NE) sdst[tid] = ei[NE + tid];
    if (tid < NN + 1) scnt[tid] = 0;
    __syncthreads();
    if (tid < NN) {
      int c = 0;
      for (int e = 0; e < NE; ++e) c += (sdst[e] == tid) ? 1 : 0;
      scnt[tid + 1] = c;
    }
    __syncthreads();
    if (tid == 0) {
      int acc = 0;
      coff[0] = 0;
#pragma unroll
      for (int n = 0; n < NN; ++n) {
        acc += scnt[n + 1];
        scnt[n + 1] = acc;
        coff[n + 1] = acc;
      }
    }
    __syncthreads();
    if (tid < NN) {
      int p = scnt[tid];                // start offset for node tid
      for (int e = 0; e < NE; ++e)
        if (sdst[e] == tid) ceid[p++] = e;
    }
  }
}

// ---------------- kernel 1: fused GATv2 L1+L2 (MFMA mid-section) ------------
// LDS tile xlds[48][XS=520] (bf16), padded row stride; edge scores
// vectorized bf16x8 (identical FP summation order). (round-7 proven version)
__global__ __launch_bounds__(256) void gat_fused_kernel(
    const float* __restrict__ x, const int* __restrict__ ei,
    const int* __restrict__ coff, const int* __restrict__ ceid,
    const float* __restrict__ Wl1, const float* __restrict__ Wr1,
    const float* __restrict__ att1, const float* __restrict__ b1,
    const u16* __restrict__ WTc,
    const float* __restrict__ att2, const float* __restrict__ b2,
    u16* __restrict__ h2b)
{
  __shared__ __attribute__((aligned(16))) u16 xlds[NN * XS];   // 48.75KB
  __shared__ float sWl1[NF * KH], sWr1[NF * KH];   // 8KB
  __shared__ float satt[KH];            // att1 then att2
  __shared__ float sbias[KH];           // b1 then b2
  __shared__ float sx[NN * NF];
  __shared__ float esc[NE * NK];
  __shared__ int soff[NN + 1];
  __shared__ u16 seid[NE], ssrc[NE], sdst[NE];

  const int tid = threadIdx.x;
  const int g = blockIdx.x;
  const int lane = tid & 63, wv = tid >> 6;
  const int l15 = lane & 15, q = lane >> 4;

#pragma unroll
  for (int rep = 0; rep < 4; ++rep) {
    int idx = rep * 256 + tid;
    sWl1[idx] = Wl1[idx];
    sWr1[idx] = Wr1[idx];
  }
  satt[tid] = att1[tid];
  sbias[tid] = b1[tid];
  if (tid < NN * NF) sx[tid] = x[(size_t)g * (NN * NF) + tid];
  if (tid < NE) {
    ssrc[tid] = (u16)ei[tid];
    sdst[tid] = (u16)ei[NE + tid];
    seid[tid] = (u16)ceid[tid];
  }
  if (tid < NN + 1) soff[tid] = coff[tid];
  __syncthreads();

  // ---- L1 transforms once: thread owns column o=tid ----
  {
    float w0 = sWl1[tid], w1 = sWl1[256 + tid], w2 = sWl1[512 + tid], w3 = sWl1[768 + tid];
    float v0 = sWr1[tid], v1 = sWr1[256 + tid], v2 = sWr1[512 + tid], v3 = sWr1[768 + tid];
#pragma unroll 4
    for (int n = 0; n < NN; ++n) {
      float x0 = sx[n * 4 + 0], x1 = sx[n * 4 + 1], x2 = sx[n * 4 + 2], x3 = sx[n * 4 + 3];
      float xl = fmaf(x3, w3, fmaf(x2, w2, fmaf(x1, w1, x0 * w0)));
      float xr = fmaf(x3, v3, fmaf(x2, v2, fmaf(x1, v1, x0 * v0)));
      xlds[n * XS + tid] = f2bf(xl);
      xlds[n * XS + 256 + tid] = f2bf(xr);
    }
  }
  __syncthreads();

  // ---- L1 edge scores (vectorized bf16x8) ----
  for (int e = tid; e < NE; e += 256) {
    int s = ssrc[e], d = sdst[e];
    const u16* xls = xlds + s * XS;
    const u16* xrd = xlds + d * XS + 256;
#pragma unroll
    for (int k = 0; k < 4; ++k) {
      float acc = 0.f;
#pragma unroll
      for (int c = 0; c < 8; ++c) {
        bf16x8 av = *(const bf16x8*)(xls + k * 64 + c * 8);
        bf16x8 bv = *(const bf16x8*)(xrd + k * 64 + c * 8);
        const float* ap = satt + k * 64 + c * 8;
#pragma unroll
        for (int j = 0; j < 8; ++j) {
          float tv = bf2f((u16)av[j]) + bf2f((u16)bv[j]);
          tv = tv > 0.f ? tv : 0.2f * tv;
          acc = fmaf(tv, ap[j], acc);
        }
      }
      esc[e * 4 + k] = acc;
    }
  }
  __syncthreads();

  // ---- L1 softmax per (n,k) ----
  if (tid < NN * NK) {
    int n = tid >> 2, k = tid & 3;
    int e0 = soff[n], e1 = soff[n + 1];
    if (e1 > e0) {
      float m = -1e30f;
      for (int j = e0; j < e1; ++j) m = fmaxf(m, esc[seid[j] * 4 + k]);
      float den = 0.f;
      for (int j = e0; j < e1; ++j) {
        float pv = expf(esc[seid[j] * 4 + k] - m);
        esc[seid[j] * 4 + k] = pv;
        den += pv;
      }
      float inv = 1.f / (den + 1e-16f);
      for (int j = e0; j < e1; ++j) esc[seid[j] * 4 + k] *= inv;
    }
  }
  __syncthreads();

  // ---- L1 aggregate -> h1 bf16 into cols 256-511 (xr dead); att2 reload ----
  satt[tid] = att2[tid];
  {
    int o = tid, k = o >> 6;
    for (int n = 0; n < NN; ++n) {
      int e0 = soff[n], e1 = soff[n + 1];
      float acc = 0.f;
      for (int j = e0; j < e1; ++j) {
        int e = seid[j];
        int s = ssrc[e];
        acc = fmaf(esc[e * 4 + k], bf2f(xlds[s * XS + o]), acc);
      }
      float ov = acc + sbias[o];
      xlds[n * XS + 256 + o] = f2bf(fmaxf(ov, 0.f));
    }
  }
  __syncthreads();
  if (tid < NH) sbias[tid] = b2[tid];

  // ---- MFMA: A-frags (h1) from LDS into VGPRs ----
  bf16x8 afr[3][8];
#pragma unroll
  for (int mt = 0; mt < 3; ++mt)
#pragma unroll
    for (int kt = 0; kt < 8; ++kt)
      afr[mt][kt] = *(const bf16x8*)(xlds + (mt * 16 + l15) * XS + 256 + kt * 32 + q * 8);
  __syncthreads();   // all A-frags in regs before outputs overwrite the tile

  // wave wv owns n-tiles [wv*8, wv*8+8)
#pragma unroll
  for (int t = 0; t < 8; ++t) {
    int n0 = (wv * 8 + t) * 16;
    const u16* bcol = WTc + (size_t)(n0 + l15) * KH + q * 8;
    f32x4 acc0 = {0.f, 0.f, 0.f, 0.f}, acc1 = acc0, acc2 = acc0;
#pragma unroll
    for (int kt = 0; kt < 8; ++kt) {
      bf16x8 bfr = *(const bf16x8*)(bcol + kt * 32);
      acc0 = __builtin_amdgcn_mfma_f32_16x16x32_bf16(afr[0][kt], bfr, acc0, 0, 0, 0);
      acc1 = __builtin_amdgcn_mfma_f32_16x16x32_bf16(afr[1][kt], bfr, acc1, 0, 0, 0);
      acc2 = __builtin_amdgcn_mfma_f32_16x16x32_bf16(afr[2][kt], bfr, acc2, 0, 0, 0);
    }
#pragma unroll
    for (int r = 0; r < 4; ++r) {
      int rw = q * 4 + r;
      xlds[(0 * 16 + rw) * XS + n0 + l15] = f2bf(acc0[r]);
      xlds[(1 * 16 + rw) * XS + n0 + l15] = f2bf(acc1[r]);
      xlds[(2 * 16 + rw) * XS + n0 + l15] = f2bf(acc2[r]);
    }
  }
  __syncthreads();

  // ---- L2 edge scores (vectorized bf16x8) ----
  for (int e = tid; e < NE; e += 256) {
    int s = ssrc[e], d = sdst[e];
    const u16* xls = xlds + s * XS;
    const u16* xrd = xlds + d * XS + 256;
#pragma unroll
    for (int k = 0; k < 4; ++k) {
      float acc = 0.f;
#pragma unroll
      for (int c = 0; c < 8; ++c) {
        bf16x8 av = *(const bf16x8*)(xls + k * 64 + c * 8);
        bf16x8 bv = *(const bf16x8*)(xrd + k * 64 + c * 8);
        const float* ap = satt + k * 64 + c * 8;
#pragma unroll
        for (int j = 0; j < 8; ++j) {
          float tv = bf2f((u16)av[j]) + bf2f((u16)bv[j]);
          tv = tv > 0.f ? tv : 0.2f * tv;
          acc = fmaf(tv, ap[j], acc);
        }
      }
      esc[e * 4 + k] = acc;
    }
  }
  __syncthreads();

  // ---- L2 softmax ----
  if (tid < NN * NK) {
    int n = tid >> 2, k = tid & 3;
    int e0 = soff[n], e1 = soff[n + 1];
    if (e1 > e0) {
      float m = -1e30f;
      for (int j = e0; j < e1; ++j) m = fmaxf(m, esc[seid[j] * 4 + k]);
      float den = 0.f;
      for (int j = e0; j < e1; ++j) {
        float pv = expf(esc[seid[j] * 4 + k] - m);
        esc[seid[j] * 4 + k] = pv;
        den += pv;
      }
      float inv = 1.f / (den + 1e-16f);
      for (int j = e0; j < e1; ++j) esc[seid[j] * 4 + k] *= inv;
    }
  }
  __syncthreads();

  // ---- L2 aggregate, mean over k, +bias, relu -> h2 bf16 global ----
  for (int task = tid; task < NN * NH; task += 256) {
    int n = task >> 6, h = task & 63;
    int e0 = soff[n], e1 = soff[n + 1];
    float acc = 0.f;
    for (int j = e0; j < e1; ++j) {
      int e = seid[j];
      int s = ssrc[e];
      const u16* xls = xlds + s * XS + h;
#pragma unroll
      for (int k = 0; k < 4; ++k)
        acc = fmaf(esc[e * 4 + k], bf2f(xls[k * 64]), acc);
    }
    float ov = fmaf(acc, 0.25f, sbias[h]);
    h2b[(size_t)g * SEQD + task] = f2bf(fmaxf(ov, 0.f));
  }
}

// ---------------- kernel 3: xw = seq @ W_ih^T + bias, bf16 MFMA -------------
// Grid 256 blocks (16 gt x 16 rt), tile M=64 x N=128, 256 threads (4 waves).
__global__ __launch_bounds__(256) void xw_mfma_kernel(const u16* __restrict__ h2b,
                                                      const u16* __restrict__ WihB,
                                                      const float* __restrict__ bih,
                                                      const float* __restrict__ bhh,
                                                      float* __restrict__ xw)
{
  const int tid = threadIdx.x, lane = tid & 63, wv = tid >> 6;
  const int l15 = lane & 15, q = lane >> 4;
  const int gt = blockIdx.x & 15, rt = blockIdx.x >> 4;
  const int g0 = gt * 64, r0 = rt * 128;

  const u16* arow[4];
#pragma unroll
  for (int mt = 0; mt < 4; ++mt)
    arow[mt] = h2b + (size_t)(g0 + mt * 16 + l15) * SEQD + q * 8;
  const u16* brow[2];
  int ncol[2];
#pragma unroll
  for (int tn = 0; tn < 2; ++tn) {
    ncol[tn] = r0 + (wv * 2 + tn) * 16 + l15;
    brow[tn] = WihB + (size_t)ncol[tn] * SEQD + q * 8;
  }

  f32x4 acc[4][2];
#pragma unroll
  for (int mt = 0; mt < 4; ++mt)
#pragma unroll
    for (int tn = 0; tn < 2; ++tn) acc[mt][tn] = (f32x4){0.f, 0.f, 0.f, 0.f};

  for (int kt = 0; kt < SEQD / 32; ++kt) {
    bf16x8 af[4], bfv[2];
#pragma unroll
    for (int mt = 0; mt < 4; ++mt) af[mt] = *(const bf16x8*)(arow[mt] + kt * 32);
#pragma unroll
    for (int tn = 0; tn < 2; ++tn) bfv[tn] = *(const bf16x8*)(brow[tn] + kt * 32);
#pragma unroll
    for (int mt = 0; mt < 4; ++mt)
#pragma unroll
      for (int tn = 0; tn < 2; ++tn)
        acc[mt][tn] = __builtin_amdgcn_mfma_f32_16x16x32_bf16(af[mt], bfv[tn], acc[mt][tn], 0, 0, 0);
  }

#pragma unroll
  for (int tn = 0; tn < 2; ++tn) {
    float bias = bih[ncol[tn]] + bhh[ncol[tn]];
#pragma unroll
    for (int mt = 0; mt < 4; ++mt)
#pragma unroll
      for (int r = 0; r < 4; ++r) {
        int gg = g0 + mt * 16 + q * 4 + r;
        xw[(size_t)gg * G4 + ncol[tn]] = acc[mt][tn][r] + bias;
      }
  }
}

// ---------------- kernel 4: persistent LSTM + FC, self-validating pairs -----
// Single barrier per step; single-batch poll (r10-proven; r2/r3/r4/r11
// alternatives all slower); pair-split finish (r10-proven).
__global__ __launch_bounds__(256) void lstm_kernel(const float* __restrict__ xw,
                                                   const float* __restrict__ Whh,
                                                   const float* __restrict__ fcw,
                                                   const float* __restrict__ fcb,
                                                   u64* pairs,
                                                   float* __restrict__ out)
{
  __shared__ float hlds[NB * NLH];     // 8KB
  __shared__ float part[2][8][32][4];  // 8KB, parity-buffered
  __shared__ float clds[8][4];
  __shared__ float fcpart[32][8];

  const int tid = threadIdx.x;
  const int blk = blockIdx.x;
  const int r32 = tid & 31, p = tid >> 5;
  const int lane = tid & 63, w = tid >> 6;
  const int R = (r32 >> 3) * NLH + blk * 8 + (r32 & 7);

  // finish mapping (wave 0, lane pairs): lane = fb*16 + fu*2 + fh
  const int fb = lane >> 4;            // batch 0..3
  const int fu = (lane >> 1) & 7;      // unit_local 0..7
  const int fh = lane & 1;             // half: gates {2fh, 2fh+1}

  float wreg[64];
  {
    const float4* wsrc = (const float4*)(Whh + (size_t)R * NLH + p * 64);
#pragma unroll
    for (int q = 0; q < 16; ++q) {
      float4 v = wsrc[q];
      wreg[4 * q + 0] = v.x; wreg[4 * q + 1] = v.y;
      wreg[4 * q + 2] = v.z; wreg[4 * q + 3] = v.w;
    }
  }
  if (tid < 32) {
    int u = tid & 7, b = tid >> 3;
    clds[u][b] = 0.f;
    __hip_atomic_store(&pairs[0 * (NB * NLH) + b * NLH + blk * 8 + u], 0ULL,
                       __ATOMIC_RELAXED, __HIP_MEMORY_SCOPE_AGENT);
  }

  for (int s = 0; s < NT; ++s) {
    // xw preload: each finish lane loads its 2 gate values (overlaps the poll)
    float myxw0, myxw1;
    if (tid < 64) {
      int un = blk * 8 + fu;
      const float* xr = xw + (size_t)(fb * NT + s) * G4 + un;
      myxw0 = xr[(2 * fh) * NLH];
      myxw1 = xr[(2 * fh + 1) * NLH];
    }
    // poll-with-data: wave w fetches its 128 units x 4 batches, 8 pairs/lane
    {
      u64* pb = pairs + (size_t)(s & 1) * (NB * NLH);
      const int u0 = w * 128 + lane, u1 = u0 + 64;
      u64 v[8];
      while (true) {
#pragma unroll
        for (int b = 0; b < NB; ++b) {
          v[2 * b]     = __hip_atomic_load(&pb[b * NLH + u0],
                                           __ATOMIC_RELAXED, __HIP_MEMORY_SCOPE_AGENT);
          v[2 * b + 1] = __hip_atomic_load(&pb[b * NLH + u1],
                                           __ATOMIC_RELAXED, __HIP_MEMORY_SCOPE_AGENT);
        }
        int mn = 0x7fffffff;
#pragma unroll
        for (int q = 0; q < 8; ++q) mn = min(mn, (int)(u32)(v[q] >> 32));
        if (__all(mn >= s)) break;
      }
#pragma unroll
      for (int b = 0; b < NB; ++b) {
        hlds[b * NLH + u0] = bitsf((u32)v[2 * b]);
        hlds[b * NLH + u1] = bitsf((u32)v[2 * b + 1]);
      }
    }
    // wave-local: hlds segment written and read only by wave w

    float a0 = 0.f, a1 = 0.f, a2 = 0.f, a3 = 0.f;
    const float* h0 = &hlds[0 * NLH + p * 64];
    const float* h1p = &hlds[1 * NLH + p * 64];
    const float* h2p = &hlds[2 * NLH + p * 64];
    const float* h3p = &hlds[3 * NLH + p * 64];
#pragma unroll
    for (int j = 0; j < 16; ++j) {
      float w0 = wreg[4 * j], w1 = wreg[4 * j + 1], w2 = wreg[4 * j + 2], w3 = wreg[4 * j + 3];
      float4 v0 = *(const float4*)(h0 + 4 * j);
      float4 v1 = *(const float4*)(h1p + 4 * j);
      float4 v2 = *(const float4*)(h2p + 4 * j);
      float4 v3 = *(const float4*)(h3p + 4 * j);
      a0 = fmaf(v0.w, w3, fmaf(v0.z, w2, fmaf(v0.y, w1, fmaf(v0.x, w0, a0))));
      a1 = fmaf(v1.w, w3, fmaf(v1.z, w2, fmaf(v1.y, w1, fmaf(v1.x, w0, a1))));
      a2 = fmaf(v2.w, w3, fmaf(v2.z, w2, fmaf(v2.y, w1, fmaf(v2.x, w0, a2))));
      a3 = fmaf(v3.w, w3, fmaf(v3.z, w2, fmaf(v3.y, w1, fmaf(v3.x, w0, a3))));
    }
    float (*pt)[32][4] = part[s & 1];
    pt[p][r32][0] = a0; pt[p][r32][1] = a1;
    pt[p][r32][2] = a2; pt[p][r32][3] = a3;
    __syncthreads();                                  // single barrier
    if (tid < 64) {
      // each lane sums its 2 gate rows (same pp order as before)
      float t0 = myxw0, t1 = myxw1;
      const int row0 = (2 * fh) * 8 + fu, row1 = (2 * fh + 1) * 8 + fu;
#pragma unroll
      for (int pp = 0; pp < 8; ++pp) t0 += pt[pp][row0][fb];
#pragma unroll
      for (int pp = 0; pp < 8; ++pp) t1 += pt[pp][row1][fb];
      // even lane: t0=i, t1=f; odd lane: t0=g, t1=o
      float e0 = fh ? tanh_fast(t0) : sigm_fast(t0);   // si | tanh(g)
      float e1 = sigm_fast(t1);                        // sf | so
      float tg = __shfl_xor(e0, 1);   // even lane receives tanh(g)
      float so = __shfl_xor(e1, 1);   // even lane receives sigm(o)
      if (fh == 0) {
        float cn = fmaf(e1, clds[fu][fb], e0 * tg);
        float hn = so * tanh_fast(cn);
        clds[fu][fb] = cn;
        u64 pk = ((u64)(u32)(s + 1) << 32) | (u64)fbits(hn);
        __hip_atomic_store(&pairs[(size_t)((s + 1) & 1) * (NB * NLH) + fb * NLH + blk * 8 + fu],
                           pk, __ATOMIC_RELAXED, __HIP_MEMORY_SCOPE_AGENT);
      }
    }
  }

  // FC on block 0
  if (blk == 0) {
    {
      u64* pb = pairs + (size_t)(NT & 1) * (NB * NLH);
      const int u0 = w * 128 + lane, u1 = u0 + 64;
      u64 v[8];
      while (true) {
#pragma unroll
        for (int b = 0; b < NB; ++b) {
          v[2 * b]     = __hip_atomic_load(&pb[b * NLH + u0],
                                           __ATOMIC_RELAXED, __HIP_MEMORY_SCOPE_AGENT);
          v[2 * b + 1] = __hip_atomic_load(&pb[b * NLH + u1],
                                           __ATOMIC_RELAXED, __HIP_MEMORY_SCOPE_AGENT);
        }
        int mn = 0x7fffffff;
#pragma unroll
        for (int q = 0; q < 8; ++q) mn = min(mn, (int)(u32)(v[q] >> 32));
        if (__all(mn >= NT)) break;
      }
#pragma unroll
      for (int b = 0; b < NB; ++b) {
        hlds[b * NLH + u0] = bitsf((u32)v[2 * b]);
        hlds[b * NLH + u1] = bitsf((u32)v[2 * b + 1]);
      }
    }
    __syncthreads();
    int pr = tid >> 3, l = tid & 7;
    int b = pr >> 3, cc = pr & 7;
    const float* hf = hlds + b * NLH;
    float a = 0.f;
    int base = cc * NLH + l * 64;
    for (int j = 0; j < 64; ++j) a = fmaf(hf[l * 64 + j], fcw[base + j], a);
    fcpart[pr][l] = a;
    __syncthreads();
    if (tid < 32) {
      float s = fcb[tid & 7];
#pragma unroll
      for (int l2 = 0; l2 < 8; ++l2) s += fcpart[tid][l2];
      out[tid] = s;
    }
  }
}

// ---------------- host ----------------
extern "C" void kernel_launch(void* const* d_in, const int* in_sizes, int n_in,
                              void* d_out, int out_size, void* d_ws, size_t ws_size,
                              hipStream_t stream)
{
  (void)in_sizes; (void)n_in; (void)out_size; (void)ws_size;
  const float* x    = (const float*)d_in[0];
  const int*   ei   = (const int*)d_in[1];
  const float* Wl1  = (const float*)d_in[2];
  const float* Wr1  = (const float*)d_in[3];
  const float* att1 = (const float*)d_in[4];
  const float* b1   = (const float*)d_in[5];
  const float* Wl2  = (const float*)d_in[6];
  const float* Wr2  = (const float*)d_in[7];
  const float* att2 = (const float*)d_in[8];
  const float* b2   = (const float*)d_in[9];
  const float* Wih  = (const float*)d_in[10];
  const float* Whh  = (const float*)d_in[11];
  const float* bih  = (const float*)d_in[12];
  const float* bhh  = (const float*)d_in[13];
  const float* fcw  = (const float*)d_in[14];
  const float* fcb  = (const float*)d_in[15];

  // workspace layout (~27.6 MB)
  char* ws = (char*)d_ws;
  int* csr_off = (int*)(ws + 0);                    // 49 ints
  int* csr_eid = (int*)(ws + 256);                  // 192 ints -> ends 1024
  u64* pairs   = (u64*)(ws + 1024);                 // 32KB -> 33792
  u16* WTc     = (u16*)(ws + 40960);                // 256KB -> 303104
  u16* WihB    = (u16*)(ws + 303104);               // 12.6MB -> 12886016
  u16* h2b     = (u16*)(ws + 12886016);             // 6MB -> 19177472
  float* xwb   = (float*)(ws + 19177472);           // 8MB -> 27566080
  float* outp  = (float*)d_out;

  prep_kernel<<<3201, 256, 0, stream>>>(Wih, WihB, Wl2, Wr2, WTc,
                                        ei, csr_off, csr_eid);
  gat_fused_kernel<<<NG, 256, 0, stream>>>(x, ei, csr_off, csr_eid,
                                           Wl1, Wr1, att1, b1,
                                           WTc, att2, b2, h2b);
  xw_mfma_kernel<<<256, 256, 0, stream>>>(h2b, WihB, bih, bhh, xwb);
  lstm_kernel<<<LSTM_NBLK, 256, 0, stream>>>(xwb, Whh, fcw, fcb, pairs, outp);
}